// Round 3
// baseline (2097.668 us; speedup 1.0000x reference)
//
#include <hip/hip_runtime.h>

// ---- problem constants ----
#define B_   2048
#define T_   512
#define H_   128
#define G_   512
#define R_   8      // batch rows per block
#define NTHR 512    // 8 waves; wave wv owns units [wv*16, wv*16+16) for both layers

typedef _Float16 f16;
typedef _Float16 f16x8 __attribute__((ext_vector_type(8)));
typedef float    f32x4 __attribute__((ext_vector_type(4)));

// ---- LDS layout (bytes). h tiles: row stride 256 B, XOR swizzle ((row&7)<<4) ----
#define OFF_RING 0                    // h1 ring: 4 slots x [8][128] f16 = 8192
#define OFF_HB   8192                 // h2 state: 2 bufs x [8][128] f16 = 4096
#define OFF_ZB   12288                // zero block [8][128] f16 = 2048 (never written)
#define OFF_XL   14336                // x: 2 bufs x 8 tok x 8 rows x 3 f32 = 1536
#define LDS_BYTES 15872

__device__ __forceinline__ float rcp_(float v) {
#if __has_builtin(__builtin_amdgcn_rcpf)
  return __builtin_amdgcn_rcpf(v);
#else
  return 1.0f / v;
#endif
}
__device__ __forceinline__ float sig_(float v)  { return rcp_(1.0f + __expf(-v)); }
__device__ __forceinline__ float tanh_(float v) { return 1.0f - 2.0f * rcp_(__expf(2.0f * v) + 1.0f); }

__device__ __forceinline__ f16x8 cvt8(const float* __restrict__ p) {
  float4 a = ((const float4*)p)[0];
  float4 b = ((const float4*)p)[1];
  f16x8 v;
  v[0]=(f16)a.x; v[1]=(f16)a.y; v[2]=(f16)a.z; v[3]=(f16)a.w;
  v[4]=(f16)b.x; v[5]=(f16)b.y; v[6]=(f16)b.z; v[7]=(f16)b.w;
  return v;
}
__device__ __forceinline__ f32x4 mfma16(f16x8 a, f16x8 b, f32x4 c) {
  return __builtin_amdgcn_mfma_f32_16x16x32_f16(a, b, c, 0, 0, 0);
}

__global__ __launch_bounds__(NTHR, 2)
void lstm_pipe(const float* __restrict__ x,
               const float* __restrict__ w_ih0, const float* __restrict__ w_hh0,
               const float* __restrict__ b_ih0, const float* __restrict__ b_hh0,
               const float* __restrict__ w_ih1, const float* __restrict__ w_hh1,
               const float* __restrict__ b_ih1, const float* __restrict__ b_hh1,
               const float* __restrict__ fc_w,  const float* __restrict__ fc_b,
               float* __restrict__ out)
{
  extern __shared__ char lds[];
  char*  ringB = lds + OFF_RING;
  char*  hBB   = lds + OFF_HB;
  char*  zb    = lds + OFF_ZB;
  float* xL    = (float*)(lds + OFF_XL);

  const int tid  = (int)threadIdx.x;
  const int lane = tid & 63;
  const int wv   = tid >> 6;
  const int n    = lane & 15;
  const int hi   = lane >> 4;
  const int u0   = wv * 16;
  const int blk  = (int)blockIdx.x;
  const int rsw  = (n & 7) << 4;

  // zero ring + hB + zeroblock (14336 B = 3584 dwords)
  for (int i = tid; i < 3584; i += NTHR) ((unsigned*)lds)[i] = 0u;
  // stage x tokens [0,8) -> xL buf0.  xL: buf*192 + tok*24 + row*3 + d
  if (tid < 192) {
    const int tok = tid / 24, rem = tid % 24, r = rem / 3, d = rem % 3;
    xL[tok*24 + r*3 + d] = x[((size_t)(blk*R_ + r)*T_ + tok)*3 + d];
  }

  // ---- resident weight fragments: 3 x 64 VGPRs ----
  f16x8 whh0f[4][4], whh1f[4][4], wih1f[4][4];
  #pragma unroll
  for (int q = 0; q < 4; ++q) {
    #pragma unroll
    for (int kc = 0; kc < 4; ++kc) {
      const int off = (q*H_ + u0 + n)*H_ + kc*32 + hi*8;
      whh0f[q][kc] = cvt8(w_hh0 + off);
      whh1f[q][kc] = cvt8(w_hh1 + off);
      wih1f[q][kc] = cvt8(w_ih1 + off);
    }
  }
  float w0d[4][3], b0[4], bP[4];
  #pragma unroll
  for (int q = 0; q < 4; ++q) {
    const int g = q*H_ + u0 + n;
    w0d[q][0] = w_ih0[g*3+0]; w0d[q][1] = w_ih0[g*3+1]; w0d[q][2] = w_ih0[g*3+2];
    b0[q] = b_ih0[g] + b_hh0[g];
    bP[q] = b_ih1[g] + b_hh1[g];
  }
  float cA0 = 0.f, cA1 = 0.f, cB0 = 0.f, cB1 = 0.f;
  f32x4 xpPair[4];
  const int  rowbase = (hi & 1)*4 + ((lane >= 32) ? 2 : 0);
  const int  colb    = 2*(u0 + n);          // byte offset of this lane's h column
  __syncthreads();

  for (int s = 0; s < T_ + 2; ++s) {
    const bool doL0 = (s < T_);
    const bool doL1 = (s >= 2);

    // x prefetch: tokens [s+8, s+16) -> other xL buf (visible by next barrier)
    if ((s & 7) == 0 && s + 8 < T_ && tid < 192) {
      const int tok = tid / 24, rem = tid % 24, r = rem / 3, d = rem % 3;
      xL[(((s >> 3) + 1) & 1)*192 + tok*24 + r*3 + d] =
          x[((size_t)(blk*R_ + r)*T_ + (s + 8 + tok))*3 + d];
    }

    // ---- proj: token pair (s-2, s-1), full 16-row M-tile, every even step ----
    if ((s & 1) == 0 && s >= 2 && s <= T_) {
      const char* pa = ringB + ((n < 8) ? (((s-2)&3)*2048) : (((s-1)&3)*2048));
      #pragma unroll
      for (int q = 0; q < 4; ++q)
        { xpPair[q][0]=bP[q]; xpPair[q][1]=bP[q]; xpPair[q][2]=bP[q]; xpPair[q][3]=bP[q]; }
      #pragma unroll
      for (int kc = 0; kc < 4; ++kc) {
        const f16x8 a = *(const f16x8*)(pa + (n&7)*256 + ((kc*64 + hi*16) ^ rsw));
        #pragma unroll
        for (int q = 0; q < 4; ++q) xpPair[q] = mfma16(a, wih1f[q][kc], xpPair[q]);
      }
    }

    // ---- layer 0: rec + update + write ----
    if (doL0) {
      f32x4 acc[4];
      const float* xb = xL + ((s >> 3) & 1)*192 + (s & 7)*24;
      #pragma unroll
      for (int q = 0; q < 4; ++q)
        #pragma unroll
        for (int r = 0; r < 4; ++r) {
          const float* xp = xb + ((hi*4 + r) & 7)*3;
          acc[q][r] = b0[q] + xp[0]*w0d[q][0] + xp[1]*w0d[q][1] + xp[2]*w0d[q][2];
        }
      const char* pa = (n < 8) ? (ringB + ((s-1)&3)*2048) : zb;
      #pragma unroll
      for (int kc = 0; kc < 4; ++kc) {
        const f16x8 a = *(const f16x8*)(pa + (n&7)*256 + ((kc*64 + hi*16) ^ rsw));
        #pragma unroll
        for (int q = 0; q < 4; ++q) acc[q] = mfma16(a, whh0f[q][kc], acc[q]);
      }
      // spread activations across all 64 lanes
      float g0[4], g1[4];
      #pragma unroll
      for (int q = 0; q < 4; ++q) {
        const float t2 = __shfl_xor(acc[q][2], 32);
        const float t3 = __shfl_xor(acc[q][3], 32);
        g0[q] = (lane >= 32) ? t2 : acc[q][0];
        g1[q] = (lane >= 32) ? t3 : acc[q][1];
      }
      {
        const float iv = sig_(g0[0]), fv = sig_(g0[1]), gv = tanh_(g0[2]), ov = sig_(g0[3]);
        cA0 = fv*cA0 + iv*gv;
        const float h = ov * tanh_(cA0);
        *(f16*)(ringB + (s&3)*2048 + rowbase*256 + (colb ^ (rowbase<<4))) = (f16)h;
      }
      {
        const float iv = sig_(g1[0]), fv = sig_(g1[1]), gv = tanh_(g1[2]), ov = sig_(g1[3]);
        cA1 = fv*cA1 + iv*gv;
        const float h = ov * tanh_(cA1);
        *(f16*)(ringB + (s&3)*2048 + (rowbase+1)*256 + (colb ^ ((rowbase+1)<<4))) = (f16)h;
      }
    }

    // ---- layer 1: rec + update + write (token s-2) ----
    if (doL1) {
      f32x4 acc[4];
      if (s & 1) {
        #pragma unroll
        for (int q = 0; q < 4; ++q)
          #pragma unroll
          for (int r = 0; r < 4; ++r) acc[q][r] = __shfl_xor(xpPair[q][r], 32);
      } else {
        #pragma unroll
        for (int q = 0; q < 4; ++q) acc[q] = xpPair[q];
      }
      const char* pb = (n < 8) ? (hBB + (s&1)*2048) : zb;
      #pragma unroll
      for (int kc = 0; kc < 4; ++kc) {
        const f16x8 a = *(const f16x8*)(pb + (n&7)*256 + ((kc*64 + hi*16) ^ rsw));
        #pragma unroll
        for (int q = 0; q < 4; ++q) acc[q] = mfma16(a, whh1f[q][kc], acc[q]);
      }
      float g0[4], g1[4];
      #pragma unroll
      for (int q = 0; q < 4; ++q) {
        const float t2 = __shfl_xor(acc[q][2], 32);
        const float t3 = __shfl_xor(acc[q][3], 32);
        g0[q] = (lane >= 32) ? t2 : acc[q][0];
        g1[q] = (lane >= 32) ? t3 : acc[q][1];
      }
      char* wr = hBB + ((s+1)&1)*2048;
      {
        const float iv = sig_(g0[0]), fv = sig_(g0[1]), gv = tanh_(g0[2]), ov = sig_(g0[3]);
        cB0 = fv*cB0 + iv*gv;
        const float h = ov * tanh_(cB0);
        *(f16*)(wr + rowbase*256 + (colb ^ (rowbase<<4))) = (f16)h;
      }
      {
        const float iv = sig_(g1[0]), fv = sig_(g1[1]), gv = tanh_(g1[2]), ov = sig_(g1[3]);
        cB1 = fv*cB1 + iv*gv;
        const float h = ov * tanh_(cB1);
        *(f16*)(wr + (rowbase+1)*256 + (colb ^ ((rowbase+1)<<4))) = (f16)h;
      }
    }
    __syncthreads();
  }

  // ---- FC head: final h2 is in hB buf[(T_+2)&1] = buf0 ----
  if (tid < R_*2) {
    const int r = tid >> 1, o = tid & 1;
    float acc = fc_b[o];
    #pragma unroll 4
    for (int d = 0; d < H_; ++d) {
      const f16 hv = *(const f16*)(hBB + r*256 + ((2*d) ^ ((r&7)<<4)));
      acc += (float)hv * fc_w[o*H_ + d];
    }
    out[(blk*R_ + r)*2 + o] = acc;
  }
}

extern "C" void kernel_launch(void* const* d_in, const int* in_sizes, int n_in,
                              void* d_out, int out_size, void* d_ws, size_t ws_size,
                              hipStream_t stream) {
  const float* x     = (const float*)d_in[0];
  const float* w_ih0 = (const float*)d_in[1];
  const float* w_hh0 = (const float*)d_in[2];
  const float* b_ih0 = (const float*)d_in[3];
  const float* b_hh0 = (const float*)d_in[4];
  const float* w_ih1 = (const float*)d_in[5];
  const float* w_hh1 = (const float*)d_in[6];
  const float* b_ih1 = (const float*)d_in[7];
  const float* b_hh1 = (const float*)d_in[8];
  const float* fc_w  = (const float*)d_in[9];
  const float* fc_b  = (const float*)d_in[10];
  (void)in_sizes; (void)n_in; (void)out_size; (void)d_ws; (void)ws_size;

  hipFuncSetAttribute((const void*)lstm_pipe,
                      hipFuncAttributeMaxDynamicSharedMemorySize, LDS_BYTES);

  lstm_pipe<<<B_/R_, NTHR, LDS_BYTES, stream>>>(
      x, w_ih0, w_hh0, b_ih0, b_hh0, w_ih1, w_hh1, b_ih1, b_hh1,
      fc_w, fc_b, (float*)d_out);
}

// Round 4
// 1255.980 us; speedup vs baseline: 1.6701x; 1.6701x over previous
//
#include <hip/hip_runtime.h>

// ---- problem constants ----
#define B_   2048
#define T_   512
#define H_   128
#define G_   512
#define R_   8      // batch rows per block
#define NTHR 512    // 8 waves; wave wv owns units [wv*16, wv*16+16) for both layers

typedef _Float16 f16;
typedef _Float16 f16x8 __attribute__((ext_vector_type(8)));
typedef float    f32x4 __attribute__((ext_vector_type(4)));

// ---- LDS layout (bytes). h tiles: row stride 256 B, XOR swizzle ((row&7)<<4) ----
#define OFF_W1   0                        // w_ih1 f16 [512][128] swizzled = 131072
#define OFF_RING 131072                   // h1 ring: 4 slots x [8][128] f16 = 8192
#define OFF_HB   139264                   // h2 state: 2 bufs x [8][128] f16 = 4096
#define OFF_ZB   143360                   // zero block [8][128] f16 = 2048 (never written)
#define OFF_XL   145408                   // x: 2 bufs x 8 tok x 8 rows x 3 f32 = 1536
#define LDS_BYTES 146944

__device__ __forceinline__ float rcp_(float v) {
#if __has_builtin(__builtin_amdgcn_rcpf)
  return __builtin_amdgcn_rcpf(v);
#else
  return 1.0f / v;
#endif
}
__device__ __forceinline__ float sig_(float v)  { return rcp_(1.0f + __expf(-v)); }
__device__ __forceinline__ float tanh_(float v) { return 1.0f - 2.0f * rcp_(__expf(2.0f * v) + 1.0f); }

__device__ __forceinline__ f16x8 cvt8(const float* __restrict__ p) {
  float4 a = ((const float4*)p)[0];
  float4 b = ((const float4*)p)[1];
  f16x8 v;
  v[0]=(f16)a.x; v[1]=(f16)a.y; v[2]=(f16)a.z; v[3]=(f16)a.w;
  v[4]=(f16)b.x; v[5]=(f16)b.y; v[6]=(f16)b.z; v[7]=(f16)b.w;
  return v;
}
__device__ __forceinline__ f32x4 mfma16(f16x8 a, f16x8 b, f32x4 c) {
  return __builtin_amdgcn_mfma_f32_16x16x32_f16(a, b, c, 0, 0, 0);
}

__global__ __launch_bounds__(NTHR, 2)
void lstm_pipe(const float* __restrict__ x,
               const float* __restrict__ w_ih0, const float* __restrict__ w_hh0,
               const float* __restrict__ b_ih0, const float* __restrict__ b_hh0,
               const float* __restrict__ w_ih1, const float* __restrict__ w_hh1,
               const float* __restrict__ b_ih1, const float* __restrict__ b_hh1,
               const float* __restrict__ fc_w,  const float* __restrict__ fc_b,
               float* __restrict__ out)
{
  extern __shared__ char lds[];
  char*  w1L   = lds + OFF_W1;
  char*  ringB = lds + OFF_RING;
  char*  hBB   = lds + OFF_HB;
  char*  zb    = lds + OFF_ZB;
  float* xL    = (float*)(lds + OFF_XL);

  const int tid  = (int)threadIdx.x;
  const int lane = tid & 63;
  const int wv   = tid >> 6;
  const int n    = lane & 15;
  const int hi   = lane >> 4;
  const int u0   = wv * 16;
  const int blk  = (int)blockIdx.x;
  const int rsw  = (n & 7) << 4;

  // ---- stage w_ih1 -> LDS f16, swizzled ----
  for (int idx = tid; idx < G_*16; idx += NTHR) {
    const int g = idx >> 4, s7 = idx & 15;
    f16x8 v = cvt8(w_ih1 + g*H_ + s7*8);
    *(f16x8*)(w1L + g*256 + ((s7*16) ^ ((g&7)<<4))) = v;
  }
  // zero ring + hB + zeroblock (OFF_RING..OFF_XL = 14336 B = 3584 dwords)
  for (int i = tid; i < 3584; i += NTHR) ((unsigned*)(lds + OFF_RING))[i] = 0u;
  // stage x tokens [0,8) -> xL buf0.  xL: buf*192 + tok*24 + row*3 + d
  if (tid < 192) {
    const int tok = tid / 24, rem = tid % 24, r = rem / 3, d = rem % 3;
    xL[tok*24 + r*3 + d] = x[((size_t)(blk*R_ + r)*T_ + tok)*3 + d];
  }

  // ---- resident weight fragments: 2 x 64 regs (fits with working set in 256) ----
  f16x8 whh0f[4][4], whh1f[4][4];
  #pragma unroll
  for (int q = 0; q < 4; ++q) {
    #pragma unroll
    for (int kc = 0; kc < 4; ++kc) {
      const int off = (q*H_ + u0 + n)*H_ + kc*32 + hi*8;
      whh0f[q][kc] = cvt8(w_hh0 + off);
      whh1f[q][kc] = cvt8(w_hh1 + off);
    }
  }
  float w0d[4][3], b0[4], bP[4];
  #pragma unroll
  for (int q = 0; q < 4; ++q) {
    const int g = q*H_ + u0 + n;
    w0d[q][0] = w_ih0[g*3+0]; w0d[q][1] = w_ih0[g*3+1]; w0d[q][2] = w_ih0[g*3+2];
    b0[q] = b_ih0[g] + b_hh0[g];
    bP[q] = b_ih1[g] + b_hh1[g];
  }
  float cA0 = 0.f, cA1 = 0.f, cB0 = 0.f, cB1 = 0.f;
  f32x4 xpPair[4];
  const int  rowbase = (hi & 1)*4 + ((lane >= 32) ? 2 : 0);
  const int  colb    = 2*(u0 + n);          // byte offset of this lane's h column
  __syncthreads();

  for (int s = 0; s < T_ + 2; ++s) {
    const bool doL0 = (s < T_);
    const bool doL1 = (s >= 2);

    // x prefetch: tokens [s+8, s+16) -> other xL buf (visible by next barrier)
    if ((s & 7) == 0 && s + 8 < T_ && tid < 192) {
      const int tok = tid / 24, rem = tid % 24, r = rem / 3, d = rem % 3;
      xL[(((s >> 3) + 1) & 1)*192 + tok*24 + r*3 + d] =
          x[((size_t)(blk*R_ + r)*T_ + (s + 8 + tok))*3 + d];
    }

    // ---- proj: token pair (s-2, s-1), full 16-row M-tile, every even step ----
    if ((s & 1) == 0 && s >= 2 && s <= T_) {
      const char* pa = ringB + ((n < 8) ? (((s-2)&3)*2048) : (((s-1)&3)*2048));
      #pragma unroll
      for (int q = 0; q < 4; ++q)
        { xpPair[q][0]=bP[q]; xpPair[q][1]=bP[q]; xpPair[q][2]=bP[q]; xpPair[q][3]=bP[q]; }
      #pragma unroll
      for (int kc = 0; kc < 4; ++kc) {
        const f16x8 a = *(const f16x8*)(pa + (n&7)*256 + ((kc*64 + hi*16) ^ rsw));
        #pragma unroll
        for (int q = 0; q < 4; ++q) {
          const f16x8 bf = *(const f16x8*)(w1L + (q*H_ + u0 + n)*256 + ((kc*64 + hi*16) ^ rsw));
          xpPair[q] = mfma16(a, bf, xpPair[q]);
        }
      }
    }

    // ---- layer 0: rec + update + write ----
    if (doL0) {
      f32x4 acc[4];
      const float* xb = xL + ((s >> 3) & 1)*192 + (s & 7)*24;
      #pragma unroll
      for (int q = 0; q < 4; ++q)
        #pragma unroll
        for (int r = 0; r < 4; ++r) {
          const float* xp = xb + ((hi*4 + r) & 7)*3;
          acc[q][r] = b0[q] + xp[0]*w0d[q][0] + xp[1]*w0d[q][1] + xp[2]*w0d[q][2];
        }
      const char* pa = (n < 8) ? (ringB + ((s-1)&3)*2048) : zb;
      #pragma unroll
      for (int kc = 0; kc < 4; ++kc) {
        const f16x8 a = *(const f16x8*)(pa + (n&7)*256 + ((kc*64 + hi*16) ^ rsw));
        #pragma unroll
        for (int q = 0; q < 4; ++q) acc[q] = mfma16(a, whh0f[q][kc], acc[q]);
      }
      // spread activations across all 64 lanes
      float g0[4], g1[4];
      #pragma unroll
      for (int q = 0; q < 4; ++q) {
        const float t2 = __shfl_xor(acc[q][2], 32);
        const float t3 = __shfl_xor(acc[q][3], 32);
        g0[q] = (lane >= 32) ? t2 : acc[q][0];
        g1[q] = (lane >= 32) ? t3 : acc[q][1];
      }
      {
        const float iv = sig_(g0[0]), fv = sig_(g0[1]), gv = tanh_(g0[2]), ov = sig_(g0[3]);
        cA0 = fv*cA0 + iv*gv;
        const float h = ov * tanh_(cA0);
        *(f16*)(ringB + (s&3)*2048 + rowbase*256 + (colb ^ (rowbase<<4))) = (f16)h;
      }
      {
        const float iv = sig_(g1[0]), fv = sig_(g1[1]), gv = tanh_(g1[2]), ov = sig_(g1[3]);
        cA1 = fv*cA1 + iv*gv;
        const float h = ov * tanh_(cA1);
        *(f16*)(ringB + (s&3)*2048 + (rowbase+1)*256 + (colb ^ ((rowbase+1)<<4))) = (f16)h;
      }
    }

    // ---- layer 1: rec + update + write (token s-2) ----
    if (doL1) {
      f32x4 acc[4];
      if (s & 1) {
        #pragma unroll
        for (int q = 0; q < 4; ++q)
          #pragma unroll
          for (int r = 0; r < 4; ++r) acc[q][r] = __shfl_xor(xpPair[q][r], 32);
      } else {
        #pragma unroll
        for (int q = 0; q < 4; ++q) acc[q] = xpPair[q];
      }
      const char* pb = (n < 8) ? (hBB + (s&1)*2048) : zb;
      #pragma unroll
      for (int kc = 0; kc < 4; ++kc) {
        const f16x8 a = *(const f16x8*)(pb + (n&7)*256 + ((kc*64 + hi*16) ^ rsw));
        #pragma unroll
        for (int q = 0; q < 4; ++q) acc[q] = mfma16(a, whh1f[q][kc], acc[q]);
      }
      float g0[4], g1[4];
      #pragma unroll
      for (int q = 0; q < 4; ++q) {
        const float t2 = __shfl_xor(acc[q][2], 32);
        const float t3 = __shfl_xor(acc[q][3], 32);
        g0[q] = (lane >= 32) ? t2 : acc[q][0];
        g1[q] = (lane >= 32) ? t3 : acc[q][1];
      }
      char* wr = hBB + ((s+1)&1)*2048;
      {
        const float iv = sig_(g0[0]), fv = sig_(g0[1]), gv = tanh_(g0[2]), ov = sig_(g0[3]);
        cB0 = fv*cB0 + iv*gv;
        const float h = ov * tanh_(cB0);
        *(f16*)(wr + rowbase*256 + (colb ^ (rowbase<<4))) = (f16)h;
      }
      {
        const float iv = sig_(g1[0]), fv = sig_(g1[1]), gv = tanh_(g1[2]), ov = sig_(g1[3]);
        cB1 = fv*cB1 + iv*gv;
        const float h = ov * tanh_(cB1);
        *(f16*)(wr + (rowbase+1)*256 + (colb ^ ((rowbase+1)<<4))) = (f16)h;
      }
    }
    __syncthreads();
  }

  // ---- FC head: final h2 is in hB buf[(T_+2)&1] = buf0 ----
  if (tid < R_*2) {
    const int r = tid >> 1, o = tid & 1;
    float acc = fc_b[o];
    #pragma unroll 4
    for (int d = 0; d < H_; ++d) {
      const f16 hv = *(const f16*)(hBB + r*256 + ((2*d) ^ ((r&7)<<4)));
      acc += (float)hv * fc_w[o*H_ + d];
    }
    out[(blk*R_ + r)*2 + o] = acc;
  }
}

extern "C" void kernel_launch(void* const* d_in, const int* in_sizes, int n_in,
                              void* d_out, int out_size, void* d_ws, size_t ws_size,
                              hipStream_t stream) {
  const float* x     = (const float*)d_in[0];
  const float* w_ih0 = (const float*)d_in[1];
  const float* w_hh0 = (const float*)d_in[2];
  const float* b_ih0 = (const float*)d_in[3];
  const float* b_hh0 = (const float*)d_in[4];
  const float* w_ih1 = (const float*)d_in[5];
  const float* w_hh1 = (const float*)d_in[6];
  const float* b_ih1 = (const float*)d_in[7];
  const float* b_hh1 = (const float*)d_in[8];
  const float* fc_w  = (const float*)d_in[9];
  const float* fc_b  = (const float*)d_in[10];
  (void)in_sizes; (void)n_in; (void)out_size; (void)d_ws; (void)ws_size;

  hipFuncSetAttribute((const void*)lstm_pipe,
                      hipFuncAttributeMaxDynamicSharedMemorySize, LDS_BYTES);

  lstm_pipe<<<B_/R_, NTHR, LDS_BYTES, stream>>>(
      x, w_ih0, w_hh0, b_ih0, b_hh0, w_ih1, w_hh1, b_ih1, b_hh1,
      fc_w, fc_b, (float*)d_out);
}